// Round 7
// baseline (794.092 us; speedup 1.0000x reference)
//
#include <hip/hip_runtime.h>
#include <hip/hip_cooperative_groups.h>
#include <stdint.h>

namespace cg = cooperative_groups;

typedef unsigned short u16;
typedef __bf16 bf16x8 __attribute__((ext_vector_type(8)));
typedef float f32x4 __attribute__((ext_vector_type(4)));
typedef u16 u16x8 __attribute__((ext_vector_type(8)));

__device__ __forceinline__ float b2f(u16 v) {
    union { float f; unsigned int u; } x; x.u = ((unsigned int)v) << 16; return x.f;
}
__device__ __forceinline__ u16 f2b(float f) {
    union { float f; unsigned int u; } x; x.f = f;
    unsigned int r = x.u + 0x7fff + ((x.u >> 16) & 1);
    return (u16)(r >> 16);
}

__device__ __forceinline__ void gll16(const void* g, void* l) {
    __builtin_amdgcn_global_load_lds(
        (const __attribute__((address_space(1))) void*)g,
        (__attribute__((address_space(3))) void*)l,
        16, 0, 0);
}

// fp32x8 -> bf16x8, round-half-up, packed via v_perm_b32.
__device__ __forceinline__ bf16x8 pack8(float4 f0, float4 f1) {
    union { float4 f; uint4 u; } a, b;
    a.f = f0; b.f = f1;
    const unsigned sel = 0x07060302u;   // D = {s0.hi16, s1.hi16}
    union { unsigned u[4]; bf16x8 v; } r;
    r.u[0] = __builtin_amdgcn_perm(a.u.y + 0x8000u, a.u.x + 0x8000u, sel);
    r.u[1] = __builtin_amdgcn_perm(a.u.w + 0x8000u, a.u.z + 0x8000u, sel);
    r.u[2] = __builtin_amdgcn_perm(b.u.y + 0x8000u, b.u.x + 0x8000u, sel);
    r.u[3] = __builtin_amdgcn_perm(b.u.w + 0x8000u, b.u.z + 0x8000u, sel);
    return r.v;
}

// cvt body: 512 thr x 8 elems = 4096 elems per chunk.
__device__ __forceinline__ void cvt_body(const float* __restrict__ s,
                                         u16* __restrict__ d, int cb)
{
    const size_t i = ((size_t)cb * 512 + threadIdx.x) * 8;
    float4 f0 = *(const float4*)(s + i);
    float4 f1 = *(const float4*)(s + i + 4);
    union { bf16x8 v; u16x8 u; } r;
    r.v = pack8(f0, f1);
    *(u16x8*)(d + i) = r.u;
}

// ===================== 256x256 8-phase GEMM body =====================
// C[M,N] = act(A[M,K] * B[N,K]^T + bias[N]), bf16 in, fp32 accum, bf16 out.
// 512 thr = 8 waves (2M x 4N), per-wave 128x64 out via interleaved strips.
// LDS: caller-provided 128 KiB = 2 K-tile buffers x 4 half-regions
// {A0,A1,B0,B1}, each [128 r][64 k] bf16, XOR-chunk-swizzled:
// phys_chunk = r*8 + (c ^ (r&7)), chunk = 8 bf16.
// Sync discipline (m201): counted vmcnt waits sit BEFORE a barrier with the
// dependent ds_reads AFTER it (vmcnt is per-wave; each wave stages only a
// slice of every region). vm6 at ph3/ph7 completes the full next tile.
// XCD partition: 2x4 XCD rectangles over the tile grid; virtual bid keeps
// vbid % 8 == blockIdx % 8 so persistent blocks stay XCD-local.

#define FBAR() do { asm volatile("" ::: "memory"); \
                    __builtin_amdgcn_s_barrier();  \
                    asm volatile("" ::: "memory"); } while (0)
#define WAIT_LGKM0() asm volatile("s_waitcnt lgkmcnt(0)" ::: "memory")
#define WAIT_VM6()   asm volatile("s_waitcnt vmcnt(6)" ::: "memory")
#define WAIT_VM0()   asm volatile("s_waitcnt vmcnt(0)" ::: "memory")
#define LREG(buf, idx) (Ls + ((buf) * 4 + (idx)) * 8192)

__device__ __forceinline__ void stage_half(
    const u16* __restrict__ Mp, int rowBase, int K, int k0,
    u16* region, int t, int w)
{
#pragma unroll
    for (int it = 0; it < 2; ++it) {
        const int phys = it * 512 + t;        // chunk 0..1023
        const int r = phys >> 3;              // row 0..127
        const int c = (phys & 7) ^ (r & 7);   // swizzled source k-chunk
        gll16(Mp + (size_t)(rowBase + r) * K + (k0 + c * 8),
              (char*)region + (it * 512 + w * 64) * 16);
    }
}

__device__ __forceinline__ void ld_a(const u16* region, int ra, int g0,
                                     bf16x8 (&out)[4][2])
{
#pragma unroll
    for (int mi = 0; mi < 4; ++mi)
#pragma unroll
        for (int s = 0; s < 2; ++s) {
            const int lr = mi * 32 + ra;      // ra = wr*16 + (l&15)
            out[mi][s] = *(const bf16x8*)((const char*)region +
                         (lr * 8 + ((s * 4 + g0) ^ (lr & 7))) * 16);
        }
}

__device__ __forceinline__ void ld_b(const u16* region, int rb, int g0,
                                     bf16x8 (&out)[2][2])
{
#pragma unroll
    for (int ni = 0; ni < 2; ++ni)
#pragma unroll
        for (int s = 0; s < 2; ++s) {
            const int lr = ni * 64 + rb;      // rb = wc*16 + (l&15)
            out[ni][s] = *(const bf16x8*)((const char*)region +
                         (lr * 8 + ((s * 4 + g0) ^ (lr & 7))) * 16);
        }
}

template <int MO, int NO>
__device__ __forceinline__ void mfma_quad(const bf16x8 (&af)[4][2],
                                          const bf16x8 (&bf)[2][2],
                                          f32x4 (&acc)[8][4])
{
    __builtin_amdgcn_s_setprio(1);
#pragma unroll
    for (int mi = 0; mi < 4; ++mi)
#pragma unroll
        for (int ni = 0; ni < 2; ++ni)
#pragma unroll
            for (int s = 0; s < 2; ++s)
                acc[MO + mi][NO + ni] = __builtin_amdgcn_mfma_f32_16x16x32_bf16(
                    af[mi][s], bf[ni][s], acc[MO + mi][NO + ni], 0, 0, 0);
    __builtin_amdgcn_s_setprio(0);
}

template <bool RELU>
__device__ __forceinline__ void gemm_body(
    u16* Ls,
    const u16* __restrict__ A, const u16* __restrict__ Bw,
    const float* __restrict__ bias, u16* __restrict__ C,
    int N, int K, int gy, int gx, int bid)
{
    const int t = threadIdx.x;
    const int l = t & 63;
    const int w = t >> 6;
    const int wr = w >> 2;    // 0..1
    const int wc = w & 3;     // 0..3

    // 2x4 rectangular XCD partition (bijective; needs gy%2==0, gx%4==0).
    const int xcd = bid & 7, rem = bid >> 3;
    const int rrows = gy >> 1, rcols = gx >> 2;
    const int lr_ = rem / rcols, lc_ = rem % rcols;
    const int mBase = ((xcd >> 2) * rrows + lr_) * 256;
    const int nBase = ((xcd & 3) * rcols + lc_) * 256;

    const int frow = l & 15;
    const int g0 = l >> 4;
    const int ra = wr * 16 + frow;
    const int rb = wc * 16 + frow;

    f32x4 acc[8][4] = {};
    bf16x8 a0[4][2], a1[4][2], b0[2][2], b1[2][2];

    const int NI = K >> 7;   // K/128; requires K multiple of 128, K >= 256

    // prologue: tile0 -> buf0 (all 4 halves first!), tile1 -> buf1 (3 halves)
    stage_half(A,  mBase,       K, 0,  LREG(0, 0), t, w);
    stage_half(Bw, nBase,       K, 0,  LREG(0, 2), t, w);
    stage_half(Bw, nBase + 128, K, 0,  LREG(0, 3), t, w);
    stage_half(A,  mBase + 128, K, 0,  LREG(0, 1), t, w);
    stage_half(A,  mBase,       K, 64, LREG(1, 0), t, w);
    stage_half(Bw, nBase,       K, 64, LREG(1, 2), t, w);
    stage_half(Bw, nBase + 128, K, 64, LREG(1, 3), t, w);
    WAIT_VM6();          // completes the 8 oldest = all of tile0 (buf0)
    FBAR();              // -> buf0 globally visible before any ph0 read

    for (int i = 0; i < NI; ++i) {
        const bool nl = (i + 1 < NI);
        const int kT1 = (2 * i + 1) << 6;
        const int kT2 = (2 * i + 2) << 6;
        const int kT3 = (2 * i + 3) << 6;

        // ---- phase 0 ----
        ld_a(LREG(0, 0), ra, g0, a0);
        ld_b(LREG(0, 2), rb, g0, b0);
        stage_half(A, mBase + 128, K, kT1, LREG(1, 1), t, w);     // (2i+1).A1
        FBAR();
        WAIT_LGKM0();
        mfma_quad<0, 0>(a0, b0, acc);
        FBAR();

        // ---- phase 1 ----
        ld_b(LREG(0, 3), rb, g0, b1);
        if (nl) stage_half(A, mBase, K, kT2, LREG(0, 0), t, w);   // (2i+2).A0
        FBAR();
        WAIT_LGKM0();
        mfma_quad<0, 2>(a0, b1, acc);
        FBAR();

        // ---- phase 2 ----
        ld_a(LREG(0, 1), ra, g0, a1);
        if (nl) stage_half(Bw, nBase, K, kT2, LREG(0, 2), t, w);  // (2i+2).B0
        FBAR();
        WAIT_LGKM0();
        mfma_quad<4, 0>(a1, b0, acc);
        FBAR();

        // ---- phase 3 ----  (wait BEFORE barrier; ph4 reads AFTER it)
        if (nl) stage_half(Bw, nBase + 128, K, kT2, LREG(0, 3), t, w); // .B1
        FBAR();
        mfma_quad<4, 2>(a1, b1, acc);
        if (nl) { WAIT_VM6(); } else { WAIT_VM0(); }
        FBAR();

        // ---- phase 4 ----
        ld_a(LREG(1, 0), ra, g0, a0);
        ld_b(LREG(1, 2), rb, g0, b0);
        if (nl) stage_half(A, mBase + 128, K, kT2, LREG(0, 1), t, w); // .A1
        FBAR();
        WAIT_LGKM0();
        mfma_quad<0, 0>(a0, b0, acc);
        FBAR();

        // ---- phase 5 ----
        ld_b(LREG(1, 3), rb, g0, b1);
        if (nl) stage_half(A, mBase, K, kT3, LREG(1, 0), t, w);   // (2i+3).A0
        FBAR();
        WAIT_LGKM0();
        mfma_quad<0, 2>(a0, b1, acc);
        FBAR();

        // ---- phase 6 ----
        ld_a(LREG(1, 1), ra, g0, a1);
        if (nl) stage_half(Bw, nBase, K, kT3, LREG(1, 2), t, w);  // (2i+3).B0
        FBAR();
        WAIT_LGKM0();
        mfma_quad<4, 0>(a1, b0, acc);
        FBAR();

        // ---- phase 7 ----  (wait BEFORE barrier; next ph0 reads AFTER it)
        if (nl) stage_half(Bw, nBase + 128, K, kT3, LREG(1, 3), t, w); // .B1
        FBAR();
        mfma_quad<4, 2>(a1, b1, acc);
        if (nl) { WAIT_VM6(); }
        FBAR();
    }

    // epilogue: C/D layout col = l&15, row = (l>>4)*4 + reg
    const int rq = (l >> 4) * 4;
#pragma unroll
    for (int ni = 0; ni < 4; ++ni) {
        const int col = nBase + ni * 64 + wc * 16 + (l & 15);
        const float bv = bias[col];
#pragma unroll
        for (int mi = 0; mi < 8; ++mi) {
            const int row = mBase + mi * 32 + wr * 16 + rq;
#pragma unroll
            for (int i2 = 0; i2 < 4; ++i2) {
                float v = acc[mi][ni][i2] + bv;
                if (RELU) v = fmaxf(v, 0.0f);
                C[(size_t)(row + i2) * N + col] = f2b(v);
            }
        }
    }
}

// Fast transcendentals via hardware exp (v_exp_f32). Overflow-safe.
__device__ __forceinline__ float fsig(float x) {
    return 1.f / (1.f + __expf(-x));
}
__device__ __forceinline__ float ftanh(float x) {
    float t = __expf(2.f * fabsf(x));
    return copysignf(1.f - 2.f / (t + 1.f), x);
}

struct PK {
    const float *inputs, *h0, *W1, *b1, *Wih, *Whh, *bih, *bhh, *W2, *b2;
    float *out, *hout;
    u16 *h0b, *Whhb, *W1b, *inb, *Wihb, *xb, *W2b, *gh, *gi, *hbf, *q;
};

// ===================== persistent cooperative kernel =====================
// 256 blocks x 512 thr, 128 KiB LDS -> exactly 1 block/CU, co-resident.
// Stages separated by grid.sync() (device-scope fence -> cross-XCD safe):
//  S0: cvt h0,Whh,W1,inputs,Wih (9728 chunks, 38/block)
//  S1: gh GEMM (384 tiles) + x GEMM (128); blocks 0-127: gh+gh,
//      blocks 128-255: gh+x+W2cvt(16 chunks)  [balanced ~2 tiles/block]
//  S2: gi GEMM (384): all blocks 1 tile, blocks 0-127 a 2nd
//  S3: GRU (2048 units of 4096 elems, 8/block)
//  S4: q GEMM (256, 1/block)
//  S5: decode (16 rows/block, LDS reused as float[4096])
// Virtual tile bids keep vbid%8 == blockIdx%8 (all strides mult of 8).
__global__ __launch_bounds__(512, 2) void persist(PK p)
{
    __shared__ alignas(16) u16 L[2 * 4 * 8192];
    cg::grid_group grid = cg::this_grid();
    const int b = blockIdx.x;          // 0..255
    const int t = threadIdx.x;

    // ---- S0: cvt (segments: 2048 h0 | 3072 Whh | 512 W1 | 1024 in | 3072 Wih)
    for (int c = b; c < 9728; c += 256) {
        if (c < 2048)       cvt_body(p.h0,  p.h0b,  c);
        else if (c < 5120)  cvt_body(p.Whh, p.Whhb, c - 2048);
        else if (c < 5632)  cvt_body(p.W1,  p.W1b,  c - 5120);
        else if (c < 6656)  cvt_body(p.inputs, p.inb, c - 5632);
        else                cvt_body(p.Wih, p.Wihb, c - 6656);
    }
    grid.sync();

    // ---- S1: gh (16x24 grid) + x (16x8 grid) + W2 cvt filler
    gemm_body<false>(L, p.h0b, p.Whhb, p.bhh, p.gh, 6144, 2048, 16, 24, b);
    if (b < 128) {
        gemm_body<false>(L, p.h0b, p.Whhb, p.bhh, p.gh, 6144, 2048, 16, 24,
                         256 + b);
    } else {
        gemm_body<true>(L, p.inb, p.W1b, p.b1, p.xb, 2048, 1024, 16, 8,
                        b - 128);
        for (int c = b - 128; c < 2048; c += 128) cvt_body(p.W2, p.W2b, c);
    }
    grid.sync();

    // ---- S2: gi (16x24 grid); gi overlays h0b/Whhb/W1b/inb (all dead)
    gemm_body<false>(L, p.xb, p.Wihb, p.bih, p.gi, 6144, 2048, 16, 24, b);
    if (b < 128)
        gemm_body<false>(L, p.xb, p.Wihb, p.bih, p.gi, 6144, 2048, 16, 24,
                         256 + b);
    grid.sync();

    // ---- S3: GRU. unit u = 4096 elems (512 thr x 8); hbf overlays Wihb.
    for (int u = b; u < 2048; u += 256) {
        const size_t idx = (size_t)u * 4096 + (size_t)t * 8;
        const size_t row = idx >> 11;          // H = 2048
        const size_t j = idx & 2047;
        const size_t g0 = row * 6144 + j;
        u16x8 vir = *(const u16x8*)&p.gi[g0];
        u16x8 viz = *(const u16x8*)&p.gi[g0 + 2048];
        u16x8 vin = *(const u16x8*)&p.gi[g0 + 4096];
        u16x8 vhr = *(const u16x8*)&p.gh[g0];
        u16x8 vhz = *(const u16x8*)&p.gh[g0 + 2048];
        u16x8 vhn = *(const u16x8*)&p.gh[g0 + 4096];
        float4 hp0 = *(const float4*)&p.h0[idx];
        float4 hp1 = *(const float4*)&p.h0[idx + 4];
        float hp[8] = {hp0.x, hp0.y, hp0.z, hp0.w,
                       hp1.x, hp1.y, hp1.z, hp1.w};
        float ho[8];
        u16x8 ob;
#pragma unroll
        for (int i = 0; i < 8; ++i) {
            float r = fsig(b2f(vir[i]) + b2f(vhr[i]));
            float z = fsig(b2f(viz[i]) + b2f(vhz[i]));
            float n = ftanh(b2f(vin[i]) + r * b2f(vhn[i]));
            float h = (1.f - z) * n + z * hp[i];
            ho[i] = h;
            ob[i] = f2b(h);
        }
        *(float4*)&p.hout[idx]     = make_float4(ho[0], ho[1], ho[2], ho[3]);
        *(float4*)&p.hout[idx + 4] = make_float4(ho[4], ho[5], ho[6], ho[7]);
        *(u16x8*)&p.hbf[idx] = ob;
    }
    grid.sync();

    // ---- S4: q GEMM (16x16 grid, 256 tiles); q overlays gh (dead)
    gemm_body<false>(L, p.hbf, p.W2b, p.b2, p.q, 4096, 2048, 16, 16, b);
    grid.sync();

    // ---- S5: decode. LDS reused as float[4096]. rows b + 256k.
    float* s = (float*)L;
    for (int k = 0; k < 16; ++k) {
        const int row = b + 256 * k;
        const size_t base = (size_t)row * 4096;
        {
            const int j = t * 8;
            u16x8 v = *(const u16x8*)&p.q[base + j];
#pragma unroll
            for (int e = 0; e < 8; ++e) s[j + e] = b2f(v[e]);
        }
        __syncthreads();
        if (t < 64) {
            float m = -INFINITY;
#pragma unroll 8
            for (int kk = 0; kk < 64; ++kk) m = fmaxf(m, s[t + kk]);
            p.out[(size_t)(2 * row) * 64 + t] = m;
        } else if (t < 128) {
            const int rr = t - 64;
            float m = -INFINITY;
#pragma unroll 8
            for (int kk = 0; kk < 64; ++kk) m = fmaxf(m, s[rr + 64 * kk]);
            const int j = (rr + 1) & 63;
            p.out[(size_t)(2 * row + 1) * 64 + j] = m;
        }
        __syncthreads();
    }
}

extern "C" void kernel_launch(void* const* d_in, const int* in_sizes, int n_in,
                              void* d_out, int out_size, void* d_ws, size_t ws_size,
                              hipStream_t stream) {
    constexpr int Bn = 4096, A = 64;

    PK p;
    p.inputs = (const float*)d_in[0];
    p.h0     = (const float*)d_in[1];
    p.W1     = (const float*)d_in[2];
    p.b1     = (const float*)d_in[3];
    p.Wih    = (const float*)d_in[4];
    p.Whh    = (const float*)d_in[5];
    p.bih    = (const float*)d_in[6];
    p.bhh    = (const float*)d_in[7];
    p.W2     = (const float*)d_in[8];
    p.b2     = (const float*)d_in[9];

    p.out  = (float*)d_out;                       // [2B, A] fp32
    p.hout = p.out + (size_t)2 * Bn * A;          // [B, H] fp32

    // ws layout (u16), stage-precise lifetimes — peak 163.6 MB:
    //  [0, 27262976): h0b | Whhb | W1b | inb  (S0->S1)  -> gi (S2->S3)
    //  [27262976, 39845888): Wihb (S0->S2)              -> hbf (S3->S4)
    //  [39845888, 48234496): xb  (S1->S2)
    //  [48234496, 56623104): W2b (S1->S4)
    //  [56623104, 81788928): gh  (S1->S3)               -> q (S4->S5)
    u16* wsu = (u16*)d_ws;
    p.h0b  = wsu;
    p.Whhb = wsu + 8388608;
    p.W1b  = wsu + 20971520;
    p.inb  = wsu + 23068672;
    p.gi   = wsu;                 // overlays the four cvt buffers (dead)
    p.Wihb = wsu + 27262976;
    p.hbf  = wsu + 27262976;      // overlays Wihb (dead after S2)
    p.xb   = wsu + 39845888;
    p.W2b  = wsu + 48234496;
    p.gh   = wsu + 56623104;
    p.q    = wsu + 56623104;      // overlays gh (dead after S3)

    void* args[] = { &p };
    hipLaunchCooperativeKernel(reinterpret_cast<void*>(&persist),
                               dim3(256), dim3(512), args, 0, stream);
}